// Round 7
// baseline (374.387 us; speedup 1.0000x reference)
//
#include <hip/hip_runtime.h>
#include <stdint.h>

// Problem sizes (fixed by reference)
constexpr int Bb = 8;      // batch
constexpr int Ss = 2048;   // sequence
constexpr int Dd = 1024;   // model dim (K of GEMM)
constexpr int Oo = 1024;   // expert out dim (N of GEMM)
constexpr int Ee = 8;      // experts

typedef __bf16 bf16x8 __attribute__((ext_vector_type(8)));
typedef float  f32x4  __attribute__((ext_vector_type(4)));

__device__ __forceinline__ unsigned short f2bf(float f) {
  unsigned int u = __float_as_uint(f);
  unsigned int r = (u + 0x7fffu + ((u >> 16) & 1u)) >> 16;
  return (unsigned short)r;
}

__device__ __forceinline__ void gl_lds16(const void* g, void* l) {
  __builtin_amdgcn_global_load_lds((const __attribute__((address_space(1))) void*)g,
                                   (__attribute__((address_space(3))) void*)l,
                                   16, 0, 0);
}

// ---------------------------------------------------------------------------
// Kernel P (fused prep): blocks [0,512): convert x->bf16 + pooled atomics;
// blocks [512,640): convert expert_w->bf16. Last-finishing pool block
// computes gates (top-2 softmax) via atomic counter — no separate launches.
// ---------------------------------------------------------------------------
__global__ __launch_bounds__(256) void k_prep(
    const float* __restrict__ x, unsigned short* __restrict__ xb,
    const float* __restrict__ w, unsigned short* __restrict__ wb,
    const float* __restrict__ gw, const float* __restrict__ gb,
    float* __restrict__ pooled, unsigned int* __restrict__ counter,
    int* __restrict__ eidx, float* __restrict__ egate) {
  const int bid = blockIdx.x;
  const int t = threadIdx.x;

  if (bid >= 512) {
    // ---- expert_w conversion: 128 blocks x 65536 elems ----
    const size_t base = (size_t)(bid - 512) * 65536;
#pragma unroll 4
    for (int it = 0; it < 64; ++it) {
      const size_t i = base + (size_t)it * 1024 + t * 4;
      float4 v = *(const float4*)(w + i);
      ushort4 o;
      o.x = f2bf(v.x); o.y = f2bf(v.y); o.z = f2bf(v.z); o.w = f2bf(v.w);
      *(ushort4*)(wb + i) = o;
    }
    return;
  }

  // ---- x conversion + pooling: 512 blocks, 32 rows each ----
  {
    const int b  = bid >> 6;
    const int sc = bid & 63;
    const size_t base = (size_t)b * Ss * Dd + (size_t)sc * 32 * Dd + t * 4;
    const float4* xp = (const float4*)(x + base);
    ushort4* xo = (ushort4*)(xb + base);
    float4 acc = make_float4(0.f, 0.f, 0.f, 0.f);
#pragma unroll 8
    for (int s = 0; s < 32; ++s) {
      float4 v = xp[(size_t)s * (Dd / 4)];
      acc.x += v.x; acc.y += v.y; acc.z += v.z; acc.w += v.w;
      ushort4 o;
      o.x = f2bf(v.x); o.y = f2bf(v.y); o.z = f2bf(v.z); o.w = f2bf(v.w);
      xo[(size_t)s * (Dd / 4)] = o;
    }
    float* pd = pooled + b * Dd + t * 4;
    atomicAdd(pd + 0, acc.x);
    atomicAdd(pd + 1, acc.y);
    atomicAdd(pd + 2, acc.z);
    atomicAdd(pd + 3, acc.w);
  }

  // ---- last pool block computes gates ----
  __shared__ unsigned s_last;
  __threadfence();
  if (t == 0) {
    unsigned v = atomicAdd(counter, 1u);
    s_last = (v == 511u) ? 1u : 0u;
  }
  __syncthreads();
  if (s_last) {
    __threadfence();
    __shared__ float slog[Bb * Ee];
    const int p = t >> 2, part = t & 3;
    const int b = p >> 3, e = p & 7;
    const float4* pv = (const float4*)(pooled + b * Dd + part * 256);
    const float4* wv = (const float4*)(gw + e * Dd + part * 256);
    float s = 0.f;
#pragma unroll
    for (int i = 0; i < 64; ++i) {
      float4 a = pv[i], wq = wv[i];
      s += a.x * wq.x + a.y * wq.y + a.z * wq.z + a.w * wq.w;
    }
    s += __shfl_xor(s, 1);
    s += __shfl_xor(s, 2);
    if (part == 0) slog[p] = s * (1.0f / (float)Ss) + gb[e];
    __syncthreads();
    if (t < Bb) {
      float m1 = -3.4e38f, m2 = -3.4e38f;
      int i1 = 0, i2 = 0;
#pragma unroll
      for (int i = 0; i < Ee; ++i) {
        const float v = slog[t * Ee + i];
        if (v > m1) { m2 = m1; i2 = i1; m1 = v; i1 = i; }
        else if (v > m2) { m2 = v; i2 = i; }
      }
      const float e2 = expf(m2 - m1);
      const float inv = 1.0f / (1.0f + e2);
      eidx[t * 2 + 0] = i1;
      eidx[t * 2 + 1] = i2;
      egate[t * 2 + 0] = inv;
      egate[t * 2 + 1] = e2 * inv;
    }
  }
}

// ---------------------------------------------------------------------------
// Kernel D: fused dual-expert GEMM, counted-vmcnt 2-phase pipeline, K-loop
// unrolled x2 so buffer/region selects fold into ds_read immediates; all LDS
// read addresses hoisted (12 VGPR offsets); setprio(1) around MFMA clusters.
// Tile: BM=128 x BN=64, BK=64, dbuf 2 x 32KB LDS. 4 waves; 32 MFMA/K-step.
// ---------------------------------------------------------------------------
constexpr int BM = 128, BN = 64, BK = 64;
constexpr int STG = 32768;
constexpr int OFF_B0 = 16384, OFF_B1 = 24576;   // B1 = B0 + 8192

__global__ __launch_bounds__(256, 2) void k_moe_gemm(
    const unsigned short* __restrict__ xb, const unsigned short* __restrict__ wb,
    const int* __restrict__ eidx, const float* __restrict__ egate,
    const float* __restrict__ expert_b, float* __restrict__ out) {
  __shared__ char lds[2 * STG];   // 64 KB

  // XCD-aware bijective swizzle: 2048 blocks, 8 XCDs -> one batch per XCD.
  const int hw = blockIdx.x;
  const int lg_id = ((hw & 7) << 8) | (hw >> 3);
  const int b  = lg_id >> 8;
  const int m0 = (lg_id & 15) * BM;
  const int n0 = ((lg_id >> 4) & 15) * BN;
  const int t  = threadIdx.x;
  const int lane = t & 63;
  const int wid  = t >> 6;
  const int wr = wid >> 1, wc = wid & 1;
  const int lr = lane & 15;
  const int lg = lane >> 4;

  const int e0 = eidx[b * 2 + 0];
  const int e1 = eidx[b * 2 + 1];
  const float g0 = egate[b * 2 + 0];
  const float g1 = egate[b * 2 + 1];

  // staging geometry (same swizzle scheme as passing R5 kernel)
  const int srow = t >> 3;
  const int scol = (((t & 7) ^ (srow & 7)) * 8);
  const int ldsoff = wid * 1024;

  // persistent global staging pointers, bumped by BK each stage
  const unsigned short* gA[4];
  const unsigned short* gB0[2];
  const unsigned short* gB1[2];
  {
    const unsigned short* Abase  = xb + (size_t)b * Ss * Dd + (size_t)m0 * Dd;
    const unsigned short* B0base = wb + (size_t)e0 * Oo * Dd + (size_t)n0 * Dd;
    const unsigned short* B1base = wb + (size_t)e1 * Oo * Dd + (size_t)n0 * Dd;
#pragma unroll
    for (int h = 0; h < 4; ++h) gA[h] = Abase + (size_t)(srow + h * 32) * Dd + scol;
#pragma unroll
    for (int h = 0; h < 2; ++h) {
      gB0[h] = B0base + (size_t)(srow + h * 32) * Dd + scol;
      gB1[h] = B1base + (size_t)(srow + h * 32) * Dd + scol;
    }
  }

  // hoisted swizzled LDS byte offsets: 6 rows x 2 ks
  int offA[2][4], offB[2][2];
#pragma unroll
  for (int ks = 0; ks < 2; ++ks) {
    const int ul = (ks << 2) | lg;
#pragma unroll
    for (int m = 0; m < 4; ++m) {
      const int r = wr * 64 + m * 16 + lr;
      offA[ks][m] = r * 128 + ((ul ^ (r & 7)) << 4);
    }
#pragma unroll
    for (int n = 0; n < 2; ++n) {
      const int r = wc * 32 + n * 16 + lr;
      offB[ks][n] = OFF_B0 + r * 128 + ((ul ^ (r & 7)) << 4);
    }
  }

  f32x4 acc0[4][2] = {};
  f32x4 acc1[4][2] = {};

  auto STAGE = [&](char* base) {
#pragma unroll
    for (int h = 0; h < 4; ++h) {
      gl_lds16(gA[h], base + h * 4096 + ldsoff);
      gA[h] += BK;
    }
#pragma unroll
    for (int h = 0; h < 2; ++h) {
      gl_lds16(gB0[h], base + OFF_B0 + h * 4096 + ldsoff);
      gl_lds16(gB1[h], base + OFF_B1 + h * 4096 + ldsoff);
      gB0[h] += BK;
      gB1[h] += BK;
    }
  };

  // COMPUTE with compile-time stage offset -> ds_read immediates carry
  // STOFF (+0/+32768) and the B1 region (+8192); zero per-step addr VALU.
#define COMPUTE_STEP(STOFF)                                                   \
  {                                                                           \
    _Pragma("unroll")                                                         \
    for (int ks = 0; ks < 2; ++ks) {                                          \
      bf16x8 af[4], bf0[2], bf1[2];                                           \
      _Pragma("unroll")                                                       \
      for (int m = 0; m < 4; ++m)                                             \
        af[m] = *(const bf16x8*)(lds + offA[ks][m] + (STOFF));                \
      _Pragma("unroll")                                                       \
      for (int n = 0; n < 2; ++n) {                                           \
        bf0[n] = *(const bf16x8*)(lds + offB[ks][n] + (STOFF));               \
        bf1[n] = *(const bf16x8*)(lds + offB[ks][n] + 8192 + (STOFF));        \
      }                                                                       \
      __builtin_amdgcn_s_setprio(1);                                          \
      _Pragma("unroll")                                                       \
      for (int m = 0; m < 4; ++m) {                                           \
        _Pragma("unroll")                                                     \
        for (int n = 0; n < 2; ++n) {                                         \
          acc0[m][n] = __builtin_amdgcn_mfma_f32_16x16x32_bf16(               \
              af[m], bf0[n], acc0[m][n], 0, 0, 0);                            \
          acc1[m][n] = __builtin_amdgcn_mfma_f32_16x16x32_bf16(               \
              af[m], bf1[n], acc1[m][n], 0, 0, 0);                            \
        }                                                                     \
      }                                                                       \
      __builtin_amdgcn_s_setprio(0);                                         \
    }                                                                         \
  }

#define PHASE(STAGE_BASE, STOFF)                                              \
  STAGE(STAGE_BASE);                                                          \
  asm volatile("s_waitcnt vmcnt(8)" ::: "memory");                            \
  __builtin_amdgcn_s_barrier();                                               \
  __builtin_amdgcn_sched_barrier(0);                                          \
  COMPUTE_STEP(STOFF);                                                        \
  __builtin_amdgcn_s_barrier();                                               \
  __builtin_amdgcn_sched_barrier(0);

  // ---- pipelined K loop: 16 K-steps, unrolled x2 (compile-time buffers) ----
  STAGE(lds);            // kt 0 -> buf0
#pragma unroll 1
  for (int i = 0; i < 7; ++i) {
    PHASE(lds + STG, 0);       // stage kt 2i+1 -> buf1, compute buf0
    PHASE(lds, STG);           // stage kt 2i+2 -> buf0, compute buf1
  }
  PHASE(lds + STG, 0);         // stage kt 15 -> buf1, compute buf0 (kt 14)
  asm volatile("s_waitcnt vmcnt(0)" ::: "memory");
  __builtin_amdgcn_s_barrier();
  __builtin_amdgcn_sched_barrier(0);
  COMPUTE_STEP(STG);           // compute buf1 (kt 15)

#undef PHASE
#undef COMPUTE_STEP

  // epilogue: out = g0*gelu(acc0+bias0) + g1*gelu(acc1+bias1)
#pragma unroll
  for (int n = 0; n < 2; ++n) {
    const int col = n0 + wc * 32 + n * 16 + lr;
    const float bias0 = expert_b[e0 * Oo + col];
    const float bias1 = expert_b[e1 * Oo + col];
#pragma unroll
    for (int m = 0; m < 4; ++m)
#pragma unroll
      for (int r = 0; r < 4; ++r) {
        const int row = m0 + wr * 64 + m * 16 + lg * 4 + r;
        const float v0 = acc0[m][n][r] + bias0;
        const float v1 = acc1[m][n][r] + bias1;
        const float ge0 = 0.5f * v0 * (1.0f + erff(v0 * 0.70710678118654752f));
        const float ge1 = 0.5f * v1 * (1.0f + erff(v1 * 0.70710678118654752f));
        out[(size_t)b * Ss * Oo + (size_t)row * Oo + col] = g0 * ge0 + g1 * ge1;
      }
  }
}

// ---------------------------------------------------------------------------
extern "C" void kernel_launch(void* const* d_in, const int* in_sizes, int n_in,
                              void* d_out, int out_size, void* d_ws, size_t ws_size,
                              hipStream_t stream) {
  const float* x        = (const float*)d_in[0];
  const float* gate_w   = (const float*)d_in[1];
  const float* gate_b   = (const float*)d_in[2];
  const float* expert_w = (const float*)d_in[3];
  const float* expert_b = (const float*)d_in[4];
  float* out = (float*)d_out;

  char* ws = (char*)d_ws;
  float* pooled = (float*)ws;                                    // 32KB
  unsigned int* counter = (unsigned int*)(ws + 32768);           // 4B
  int*   eidx   = (int*)(ws + 32832);                            // 64B
  float* egate  = (float*)(ws + 32896);                          // 64B
  unsigned short* xb = (unsigned short*)(ws + 65536);            // 32MB
  unsigned short* wb = (unsigned short*)(ws + 65536 + (size_t)Bb * Ss * Dd * 2);

  hipMemsetAsync(ws, 0, 32772, stream);   // pooled + counter

  k_prep<<<640, 256, 0, stream>>>(x, xb, expert_w, wb, gate_w, gate_b,
                                  pooled, counter, eidx, egate);
  k_moe_gemm<<<(Ss / BM) * (Oo / BN) * Bb, 256, 0, stream>>>(xb, wb, eidx, egate,
                                                             expert_b, out);
}

// Round 8
// 280.057 us; speedup vs baseline: 1.3368x; 1.3368x over previous
//
#include <hip/hip_runtime.h>
#include <stdint.h>

// Problem sizes (fixed by reference)
constexpr int Bb = 8;      // batch
constexpr int Ss = 2048;   // sequence
constexpr int Dd = 1024;   // model dim (K of GEMM)
constexpr int Oo = 1024;   // expert out dim (N of GEMM)
constexpr int Ee = 8;      // experts

typedef __bf16 bf16x8 __attribute__((ext_vector_type(8)));
typedef float  f32x4  __attribute__((ext_vector_type(4)));

__device__ __forceinline__ unsigned short f2bf(float f) {
  // round-to-nearest-even fp32 -> bf16 (inputs are finite)
  unsigned int u = __float_as_uint(f);
  unsigned int r = (u + 0x7fffu + ((u >> 16) & 1u)) >> 16;
  return (unsigned short)r;
}

__device__ __forceinline__ void gl_lds16(const void* g, void* l) {
  // async 16B global -> LDS; LDS dest is wave-uniform base + lane*16
  __builtin_amdgcn_global_load_lds((const __attribute__((address_space(1))) void*)g,
                                   (__attribute__((address_space(3))) void*)l,
                                   16, 0, 0);
}

// ---------------------------------------------------------------------------
// Kernel P: fence-free balanced prep. 768 blocks of 256:
//   blocks [0,512):  convert x fp32->bf16 + pooled column-sum atomics
//                    (each block: 32 rows = 128KB read)
//   blocks [512,768): convert expert_w fp32->bf16
//                    (each block: 32768 elems = 128KB read)
// NO __threadfence, NO atomic-counter handoff — gates runs as its own kernel
// (kernel boundary provides cross-XCD visibility of pooled).
// ---------------------------------------------------------------------------
__global__ __launch_bounds__(256) void k_prep(
    const float* __restrict__ x, unsigned short* __restrict__ xb,
    const float* __restrict__ w, unsigned short* __restrict__ wb,
    float* __restrict__ pooled) {
  const int bid = blockIdx.x;
  const int t = threadIdx.x;

  if (bid >= 512) {
    // ---- expert_w conversion: 256 blocks x 32768 elems ----
    const size_t base = (size_t)(bid - 512) * 32768 + t * 4;
    const float4* wp = (const float4*)(w + base);
    ushort4* wo = (ushort4*)(wb + base);
#pragma unroll 8
    for (int it = 0; it < 32; ++it) {
      float4 v = wp[(size_t)it * 256];
      ushort4 o;
      o.x = f2bf(v.x); o.y = f2bf(v.y); o.z = f2bf(v.z); o.w = f2bf(v.w);
      wo[(size_t)it * 256] = o;
    }
    return;
  }

  // ---- x conversion + pooling: 512 blocks, 32 rows each ----
  const int b  = bid >> 6;
  const int sc = bid & 63;
  const size_t base = (size_t)b * Ss * Dd + (size_t)sc * 32 * Dd + t * 4;
  const float4* xp = (const float4*)(x + base);
  ushort4* xo = (ushort4*)(xb + base);
  float4 acc = make_float4(0.f, 0.f, 0.f, 0.f);
#pragma unroll 8
  for (int s = 0; s < 32; ++s) {
    float4 v = xp[(size_t)s * (Dd / 4)];
    acc.x += v.x; acc.y += v.y; acc.z += v.z; acc.w += v.w;
    ushort4 o;
    o.x = f2bf(v.x); o.y = f2bf(v.y); o.z = f2bf(v.z); o.w = f2bf(v.w);
    xo[(size_t)s * (Dd / 4)] = o;
  }
  float* pd = pooled + b * Dd + t * 4;
  atomicAdd(pd + 0, acc.x);
  atomicAdd(pd + 1, acc.y);
  atomicAdd(pd + 2, acc.z);
  atomicAdd(pd + 3, acc.w);
}

// ---------------------------------------------------------------------------
// Kernel B: logits = (pooled/S) @ gate_w^T + gate_b ; compact top-2 selection
// One block, 256 threads. 4 threads per (b,e) pair.
// Emits eidx[b][2] (expert ids) and egate[b][2] (softmax weights over top-2).
// ---------------------------------------------------------------------------
__global__ __launch_bounds__(256) void k_gates(
    const float* __restrict__ pooled, const float* __restrict__ gw,
    const float* __restrict__ gb, int* __restrict__ eidx,
    float* __restrict__ egate) {
  __shared__ float slog[Bb * Ee];
  const int t = threadIdx.x;
  const int p = t >> 2, part = t & 3;
  const int b = p >> 3, e = p & 7;
  const float4* pv = (const float4*)(pooled + b * Dd + part * 256);
  const float4* wv = (const float4*)(gw + e * Dd + part * 256);
  float s = 0.f;
#pragma unroll
  for (int i = 0; i < 64; ++i) {
    float4 a = pv[i], w = wv[i];
    s += a.x * w.x + a.y * w.y + a.z * w.z + a.w * w.w;
  }
  s += __shfl_xor(s, 1);
  s += __shfl_xor(s, 2);
  if (part == 0) slog[p] = s * (1.0f / (float)Ss) + gb[e];
  __syncthreads();
  if (t < Bb) {
    float m1 = -3.4e38f, m2 = -3.4e38f;
    int i1 = 0, i2 = 0;
#pragma unroll
    for (int i = 0; i < Ee; ++i) {
      const float v = slog[t * Ee + i];
      if (v > m1) { m2 = m1; i2 = i1; m1 = v; i1 = i; }
      else if (v > m2) { m2 = v; i2 = i; }
    }
    const float e2 = expf(m2 - m1);
    const float inv = 1.0f / (1.0f + e2);
    eidx[t * 2 + 0] = i1;
    eidx[t * 2 + 1] = i2;
    egate[t * 2 + 0] = inv;
    egate[t * 2 + 1] = e2 * inv;
  }
}

// ---------------------------------------------------------------------------
// Kernel D: fused dual-expert GEMM, counted-vmcnt 2-phase pipeline (T3/T4).
// EXACT R5 version (measured 109us, MfmaUtil 27, occ 20, bank-conflicts 0).
// Tile: BM=128 (s) x BN=64 (o), BK=64, double-buffered LDS (2 x 32KB = 64KB).
// ---------------------------------------------------------------------------
constexpr int BM = 128, BN = 64, BK = 64;
constexpr int STG = 32768;        // bytes per stage
constexpr int OFF_B0 = 16384, OFF_B1 = 24576;

__global__ __launch_bounds__(256, 2) void k_moe_gemm(
    const unsigned short* __restrict__ xb, const unsigned short* __restrict__ wb,
    const int* __restrict__ eidx, const float* __restrict__ egate,
    const float* __restrict__ expert_b, float* __restrict__ out) {
  __shared__ char lds[2 * STG];   // 64 KB

  // XCD-aware bijective swizzle: 2048 blocks, 8 XCDs -> one batch per XCD.
  const int hw = blockIdx.x;
  const int lg_id = ((hw & 7) << 8) | (hw >> 3);
  const int b  = lg_id >> 8;                // batch == XCD
  const int m0 = (lg_id & 15) * BM;         // s
  const int n0 = ((lg_id >> 4) & 15) * BN;  // o
  const int t  = threadIdx.x;
  const int lane = t & 63;
  const int wid  = t >> 6;
  const int wr = wid >> 1, wc = wid & 1;    // wave -> 64x32 subtile
  const int lr = lane & 15;                 // frag row (A) / col (B,D)
  const int lg = lane >> 4;                 // frag k-group 0..3

  const int e0 = eidx[b * 2 + 0];
  const int e1 = eidx[b * 2 + 1];
  const float g0 = egate[b * 2 + 0];
  const float g1 = egate[b * 2 + 1];

  // staging geometry: thread t writes LDS linear byte t*16 (+h*4096);
  // global source column inverse-swizzled so swizzled reads see logical data
  const int srow = t >> 3;                          // 0..31 (+h*32)
  const int scol = (((t & 7) ^ (srow & 7)) * 8);    // element offset in row
  const int ldsoff = wid * 1024;                    // wave-uniform byte part

  const unsigned short* Abase  = xb + (size_t)b * Ss * Dd + (size_t)m0 * Dd;
  const unsigned short* B0base = wb + (size_t)e0 * Oo * Dd + (size_t)n0 * Dd;
  const unsigned short* B1base = wb + (size_t)e1 * Oo * Dd + (size_t)n0 * Dd;

  f32x4 acc0[4][2] = {};
  f32x4 acc1[4][2] = {};

  // ---- STAGE: issue 8 global_load_lds for K-tile kt into stage st ----
  auto STAGE = [&](int st, int kt) {
    char* base = lds + st * STG;
#pragma unroll
    for (int h = 0; h < 4; ++h) {   // A: 128 rows
      const int row = srow + h * 32;
      gl_lds16(Abase + (size_t)row * Dd + kt + scol,
               base + h * 4096 + ldsoff);
    }
#pragma unroll
    for (int h = 0; h < 2; ++h) {   // B0, B1: 64 rows each
      const int row = srow + h * 32;
      const size_t goff = (size_t)row * Dd + kt + scol;
      gl_lds16(B0base + goff, base + OFF_B0 + h * 4096 + ldsoff);
      gl_lds16(B1base + goff, base + OFF_B1 + h * 4096 + ldsoff);
    }
  };

  // ---- COMPUTE: 16 ds_read_b128 + 32 MFMA on stage st ----
  auto COMPUTE = [&](int st) {
    const char* base = lds + st * STG;
#pragma unroll
    for (int ks = 0; ks < 2; ++ks) {
      const int ul = (ks << 2) | lg;     // logical 16B unit in 128B row
      bf16x8 af[4], bf0[2], bf1[2];
#pragma unroll
      for (int m = 0; m < 4; ++m) {
        const int r = wr * 64 + m * 16 + lr;
        af[m] = *(const bf16x8*)(base + r * 128 + ((ul ^ (r & 7)) << 4));
      }
#pragma unroll
      for (int n = 0; n < 2; ++n) {
        const int r = wc * 32 + n * 16 + lr;
        bf0[n] = *(const bf16x8*)(base + OFF_B0 + r * 128 + ((ul ^ (r & 7)) << 4));
        bf1[n] = *(const bf16x8*)(base + OFF_B1 + r * 128 + ((ul ^ (r & 7)) << 4));
      }
#pragma unroll
      for (int m = 0; m < 4; ++m)
#pragma unroll
        for (int n = 0; n < 2; ++n) {
          acc0[m][n] = __builtin_amdgcn_mfma_f32_16x16x32_bf16(
              af[m], bf0[n], acc0[m][n], 0, 0, 0);
          acc1[m][n] = __builtin_amdgcn_mfma_f32_16x16x32_bf16(
              af[m], bf1[n], acc1[m][n], 0, 0, 0);
        }
    }
  };

  // ---- pipelined K loop: 16 K-steps ----
  STAGE(0, 0);
  int cur = 0;
#pragma unroll 1
  for (int kt_i = 0; kt_i < 15; ++kt_i) {
    STAGE(cur ^ 1, (kt_i + 1) * BK);                 // prefetch next (8 loads)
    asm volatile("s_waitcnt vmcnt(8)" ::: "memory"); // wait only cur's loads
    __builtin_amdgcn_s_barrier();
    __builtin_amdgcn_sched_barrier(0);
    COMPUTE(cur);
    __builtin_amdgcn_s_barrier();                    // protect buf reuse
    __builtin_amdgcn_sched_barrier(0);
    cur ^= 1;
  }
  asm volatile("s_waitcnt vmcnt(0)" ::: "memory");
  __builtin_amdgcn_s_barrier();
  __builtin_amdgcn_sched_barrier(0);
  COMPUTE(cur);

  // epilogue: out = g0*gelu(acc0+bias0) + g1*gelu(acc1+bias1), single store
#pragma unroll
  for (int n = 0; n < 2; ++n) {
    const int col = n0 + wc * 32 + n * 16 + lr;
    const float bias0 = expert_b[e0 * Oo + col];
    const float bias1 = expert_b[e1 * Oo + col];
#pragma unroll
    for (int m = 0; m < 4; ++m)
#pragma unroll
      for (int r = 0; r < 4; ++r) {
        const int row = m0 + wr * 64 + m * 16 + lg * 4 + r;
        const float v0 = acc0[m][n][r] + bias0;
        const float v1 = acc1[m][n][r] + bias1;
        const float ge0 = 0.5f * v0 * (1.0f + erff(v0 * 0.70710678118654752f));
        const float ge1 = 0.5f * v1 * (1.0f + erff(v1 * 0.70710678118654752f));
        out[(size_t)b * Ss * Oo + (size_t)row * Oo + col] = g0 * ge0 + g1 * ge1;
      }
  }
}

// ---------------------------------------------------------------------------
extern "C" void kernel_launch(void* const* d_in, const int* in_sizes, int n_in,
                              void* d_out, int out_size, void* d_ws, size_t ws_size,
                              hipStream_t stream) {
  const float* x        = (const float*)d_in[0];
  const float* gate_w   = (const float*)d_in[1];
  const float* gate_b   = (const float*)d_in[2];
  const float* expert_w = (const float*)d_in[3];
  const float* expert_b = (const float*)d_in[4];
  float* out = (float*)d_out;

  char* ws = (char*)d_ws;
  float* pooled = (float*)ws;                                    // 32KB
  int*   eidx   = (int*)(ws + 32832);                            // 64B
  float* egate  = (float*)(ws + 32896);                          // 64B
  unsigned short* xb = (unsigned short*)(ws + 65536);            // 32MB
  unsigned short* wb = (unsigned short*)(ws + 65536 + (size_t)Bb * Ss * Dd * 2);

  hipMemsetAsync(pooled, 0, Bb * Dd * sizeof(float), stream);

  k_prep<<<768, 256, 0, stream>>>(x, xb, expert_w, wb, pooled);
  k_gates<<<1, 256, 0, stream>>>(pooled, gate_w, gate_b, eidx, egate);
  k_moe_gemm<<<(Ss / BM) * (Oo / BN) * Bb, 256, 0, stream>>>(xb, wb, eidx, egate,
                                                             expert_b, out);
}

// Round 9
// 275.838 us; speedup vs baseline: 1.3573x; 1.0153x over previous
//
#include <hip/hip_runtime.h>
#include <stdint.h>

// Problem sizes (fixed by reference)
constexpr int Bb = 8;      // batch
constexpr int Ss = 2048;   // sequence
constexpr int Dd = 1024;   // model dim (K of GEMM)
constexpr int Oo = 1024;   // expert out dim (N of GEMM)
constexpr int Ee = 8;      // experts

typedef __bf16 bf16x8 __attribute__((ext_vector_type(8)));
typedef float  f32x4  __attribute__((ext_vector_type(4)));

__device__ __forceinline__ unsigned short f2bf(float f) {
  // round-to-nearest-even fp32 -> bf16 (inputs are finite)
  unsigned int u = __float_as_uint(f);
  unsigned int r = (u + 0x7fffu + ((u >> 16) & 1u)) >> 16;
  return (unsigned short)r;
}

__device__ __forceinline__ void gl_lds16(const void* g, void* l) {
  // async 16B global -> LDS; LDS dest is wave-uniform base + lane*16
  __builtin_amdgcn_global_load_lds((const __attribute__((address_space(1))) void*)g,
                                   (__attribute__((address_space(3))) void*)l,
                                   16, 0, 0);
}

// ---------------------------------------------------------------------------
// Kernel P: fence-free balanced prep (verbatim from R8). 768 blocks of 256.
// ---------------------------------------------------------------------------
__global__ __launch_bounds__(256) void k_prep(
    const float* __restrict__ x, unsigned short* __restrict__ xb,
    const float* __restrict__ w, unsigned short* __restrict__ wb,
    float* __restrict__ pooled) {
  const int bid = blockIdx.x;
  const int t = threadIdx.x;

  if (bid >= 512) {
    const size_t base = (size_t)(bid - 512) * 32768 + t * 4;
    const float4* wp = (const float4*)(w + base);
    ushort4* wo = (ushort4*)(wb + base);
#pragma unroll 8
    for (int it = 0; it < 32; ++it) {
      float4 v = wp[(size_t)it * 256];
      ushort4 o;
      o.x = f2bf(v.x); o.y = f2bf(v.y); o.z = f2bf(v.z); o.w = f2bf(v.w);
      wo[(size_t)it * 256] = o;
    }
    return;
  }

  const int b  = bid >> 6;
  const int sc = bid & 63;
  const size_t base = (size_t)b * Ss * Dd + (size_t)sc * 32 * Dd + t * 4;
  const float4* xp = (const float4*)(x + base);
  ushort4* xo = (ushort4*)(xb + base);
  float4 acc = make_float4(0.f, 0.f, 0.f, 0.f);
#pragma unroll 8
  for (int s = 0; s < 32; ++s) {
    float4 v = xp[(size_t)s * (Dd / 4)];
    acc.x += v.x; acc.y += v.y; acc.z += v.z; acc.w += v.w;
    ushort4 o;
    o.x = f2bf(v.x); o.y = f2bf(v.y); o.z = f2bf(v.z); o.w = f2bf(v.w);
    xo[(size_t)s * (Dd / 4)] = o;
  }
  float* pd = pooled + b * Dd + t * 4;
  atomicAdd(pd + 0, acc.x);
  atomicAdd(pd + 1, acc.y);
  atomicAdd(pd + 2, acc.z);
  atomicAdd(pd + 3, acc.w);
}

// ---------------------------------------------------------------------------
// Kernel B: gates (verbatim from R8). One block.
// ---------------------------------------------------------------------------
__global__ __launch_bounds__(256) void k_gates(
    const float* __restrict__ pooled, const float* __restrict__ gw,
    const float* __restrict__ gb, int* __restrict__ eidx,
    float* __restrict__ egate) {
  __shared__ float slog[Bb * Ee];
  const int t = threadIdx.x;
  const int p = t >> 2, part = t & 3;
  const int b = p >> 3, e = p & 7;
  const float4* pv = (const float4*)(pooled + b * Dd + part * 256);
  const float4* wv = (const float4*)(gw + e * Dd + part * 256);
  float s = 0.f;
#pragma unroll
  for (int i = 0; i < 64; ++i) {
    float4 a = pv[i], w = wv[i];
    s += a.x * w.x + a.y * w.y + a.z * w.z + a.w * w.w;
  }
  s += __shfl_xor(s, 1);
  s += __shfl_xor(s, 2);
  if (part == 0) slog[p] = s * (1.0f / (float)Ss) + gb[e];
  __syncthreads();
  if (t < Bb) {
    float m1 = -3.4e38f, m2 = -3.4e38f;
    int i1 = 0, i2 = 0;
#pragma unroll
    for (int i = 0; i < Ee; ++i) {
      const float v = slog[t * Ee + i];
      if (v > m1) { m2 = m1; i2 = i1; m1 = v; i1 = i; }
      else if (v > m2) { m2 = v; i2 = i; }
    }
    const float e2 = expf(m2 - m1);
    const float inv = 1.0f / (1.0f + e2);
    eidx[t * 2 + 0] = i1;
    eidx[t * 2 + 1] = i2;
    egate[t * 2 + 0] = inv;
    egate[t * 2 + 1] = e2 * inv;
  }
}

// ---------------------------------------------------------------------------
// Kernel D: dual-expert GEMM, 8-wave deep-phase template (T2+T3+T4+T5).
// BM=256 x BN=128, BK=32, 512 threads (2M x 4N waves), dbuf 2x32KB = 64KB.
// Per K-tile (32 total): boundary {4 gl_lds next-tile, vmcnt(4), barrier},
// phase-e0 {10 ds_read, bar, lgkmcnt0, setprio, 16 MFMA}, phase-e1
// {2 ds_read (A-frags reused in regs), lgkmcnt0, setprio, 16 MFMA, bar}.
// All ds_read addrs = stage-base reg + compile-time immediate (zero VALU).
// Swizzle: 16B unit u of row R at physical u^((R>>1)&3); staged via
// inverse-swizzled global source, linear LDS dest (both-sides rule).
// Stage layout (32KB): A[256][64B] @0 (2 sets), B_e0[128][64B] @16384,
// B_e1[128][64B] @24576.
// ---------------------------------------------------------------------------
constexpr int BM = 256, BN = 128, BK = 32;
constexpr int STG = 32768;
constexpr int B0_OFF = 16384, B1_OFF = 24576;

__global__ __launch_bounds__(512, 2) void k_moe_gemm(
    const unsigned short* __restrict__ xb, const unsigned short* __restrict__ wb,
    const int* __restrict__ eidx, const float* __restrict__ egate,
    const float* __restrict__ expert_b, float* __restrict__ out) {
  __shared__ char lds[2 * STG];   // 64 KB static

  // XCD-aware bijective swizzle: 512 blocks, 8 XCDs -> one batch per XCD.
  const int hw = blockIdx.x;
  const int lg_id = ((hw & 7) << 6) | (hw >> 3);
  const int b  = lg_id >> 6;                // batch == XCD
  const int wg = lg_id & 63;
  const int m0 = (wg & 7) * BM;             // s tile (8)
  const int n0 = (wg >> 3) * BN;            // o tile (8)
  const int t  = threadIdx.x;
  const int lane = t & 63;
  const int wid  = t >> 6;                  // 0..7
  const int wr = wid >> 2;                  // 0..1 (M)
  const int wc = wid & 3;                   // 0..3 (N)
  const int lr = lane & 15;
  const int lg = lane >> 4;

  const int e0 = eidx[b * 2 + 0];
  const int e1 = eidx[b * 2 + 1];
  const float g0 = egate[b * 2 + 0];
  const float g1 = egate[b * 2 + 1];

  // ---- staging geometry: thread t -> srow=t>>2 (0..127), phys unit t&3 ----
  const int srow = t >> 2;
  const int scol = ((t & 3) ^ ((srow >> 1) & 3)) * 8;  // inverse-swizzled col
  const int ldsoff = wid * 1024;                       // wave-uniform dest part

  const unsigned short* gA0 = xb + (size_t)b * Ss * Dd + (size_t)(m0 + srow) * Dd + scol;
  const unsigned short* gA1 = gA0 + (size_t)128 * Dd;
  const unsigned short* gB0 = wb + (size_t)e0 * Oo * Dd + (size_t)(n0 + srow) * Dd + scol;
  const unsigned short* gB1 = wb + (size_t)e1 * Oo * Dd + (size_t)(n0 + srow) * Dd + scol;

  // ---- hoisted ds_read base addresses (per stage); frag index -> immediate --
  const int swz = (lg ^ ((lr >> 1) & 3)) * 16;
  const int adsA0 = (wr * 128 + lr) * 64 + swz;           // + m*1024 imm
  const int adsA1 = adsA0 + STG;
  const int adsB0 = B0_OFF + (wc * 32 + lr) * 64 + swz;   // + e*8192 + n*1024 imm
  const int adsB1 = adsB0 + STG;

  f32x4 acc0[8][2] = {};
  f32x4 acc1[8][2] = {};

  auto STAGE = [&](char* base) {
    gl_lds16(gA0, base + ldsoff);              // A rows 0..127
    gl_lds16(gA1, base + 8192 + ldsoff);       // A rows 128..255
    gl_lds16(gB0, base + B0_OFF + ldsoff);     // B expert0 rows 0..127
    gl_lds16(gB1, base + B1_OFF + ldsoff);     // B expert1 rows 0..127
    gA0 += BK; gA1 += BK; gB0 += BK; gB1 += BK;
  };

#define TILE(ADSA, ADSB, STAGEBASE, DOSTAGE, VMC)                              \
  {                                                                            \
    if (DOSTAGE) STAGE(STAGEBASE);                                             \
    asm volatile("s_waitcnt vmcnt(" VMC ")" ::: "memory");                     \
    __builtin_amdgcn_s_barrier();                                              \
    __builtin_amdgcn_sched_barrier(0);                                         \
    bf16x8 af[8], bf[2];                                                       \
    _Pragma("unroll")                                                          \
    for (int m = 0; m < 8; ++m)                                                \
      af[m] = *(const bf16x8*)(lds + (ADSA) + m * 1024);                       \
    _Pragma("unroll")                                                          \
    for (int n = 0; n < 2; ++n)                                                \
      bf[n] = *(const bf16x8*)(lds + (ADSB) + n * 1024);                       \
    __builtin_amdgcn_s_barrier();                                              \
    asm volatile("s_waitcnt lgkmcnt(0)" ::: "memory");                         \
    __builtin_amdgcn_sched_barrier(0);                                         \
    __builtin_amdgcn_s_setprio(1);                                             \
    _Pragma("unroll")                                                          \
    for (int m = 0; m < 8; ++m)                                                \
      _Pragma("unroll")                                                        \
      for (int n = 0; n < 2; ++n)                                              \
        acc0[m][n] = __builtin_amdgcn_mfma_f32_16x16x32_bf16(                  \
            af[m], bf[n], acc0[m][n], 0, 0, 0);                                \
    __builtin_amdgcn_s_setprio(0);                                             \
    __builtin_amdgcn_s_barrier();                                              \
    _Pragma("unroll")                                                          \
    for (int n = 0; n < 2; ++n)                                                \
      bf[n] = *(const bf16x8*)(lds + (ADSB) + 8192 + n * 1024);                \
    asm volatile("s_waitcnt lgkmcnt(0)" ::: "memory");                         \
    __builtin_amdgcn_sched_barrier(0);                                         \
    __builtin_amdgcn_s_setprio(1);                                             \
    _Pragma("unroll")                                                          \
    for (int m = 0; m < 8; ++m)                                                \
      _Pragma("unroll")                                                        \
      for (int n = 0; n < 2; ++n)                                              \
        acc1[m][n] = __builtin_amdgcn_mfma_f32_16x16x32_bf16(                  \
            af[m], bf[n], acc1[m][n], 0, 0, 0);                                \
    __builtin_amdgcn_s_setprio(0);                                             \
    __builtin_amdgcn_s_barrier();                                              \
  }

  // ---- K loop: 32 K-tiles, unrolled x2 so stage select is compile-time ----
  STAGE(lds);                        // tile 0 -> buf0
#pragma unroll 1
  for (int i = 0; i < 15; ++i) {
    TILE(adsA0, adsB0, lds + STG, 1, "4");   // tile 2i   (buf0), stage -> buf1
    TILE(adsA1, adsB1, lds,       1, "4");   // tile 2i+1 (buf1), stage -> buf0
  }
  TILE(adsA0, adsB0, lds + STG, 1, "4");     // tile 30 (buf0), stage 31 -> buf1
  TILE(adsA1, adsB1, lds,       0, "0");     // tile 31 (buf1), no stage

#undef TILE

  // ---- epilogue: out = g0*gelu(acc0+bias0) + g1*gelu(acc1+bias1) ----
#pragma unroll
  for (int n = 0; n < 2; ++n) {
    const int col = n0 + wc * 32 + n * 16 + lr;
    const float bias0 = expert_b[e0 * Oo + col];
    const float bias1 = expert_b[e1 * Oo + col];
#pragma unroll
    for (int m = 0; m < 8; ++m)
#pragma unroll
      for (int r = 0; r < 4; ++r) {
        const int row = m0 + wr * 128 + m * 16 + lg * 4 + r;
        const float v0 = acc0[m][n][r] + bias0;
        const float v1 = acc1[m][n][r] + bias1;
        const float ge0 = 0.5f * v0 * (1.0f + erff(v0 * 0.70710678118654752f));
        const float ge1 = 0.5f * v1 * (1.0f + erff(v1 * 0.70710678118654752f));
        out[(size_t)b * Ss * Oo + (size_t)row * Oo + col] = g0 * ge0 + g1 * ge1;
      }
  }
}

// ---------------------------------------------------------------------------
extern "C" void kernel_launch(void* const* d_in, const int* in_sizes, int n_in,
                              void* d_out, int out_size, void* d_ws, size_t ws_size,
                              hipStream_t stream) {
  const float* x        = (const float*)d_in[0];
  const float* gate_w   = (const float*)d_in[1];
  const float* gate_b   = (const float*)d_in[2];
  const float* expert_w = (const float*)d_in[3];
  const float* expert_b = (const float*)d_in[4];
  float* out = (float*)d_out;

  char* ws = (char*)d_ws;
  float* pooled = (float*)ws;                                    // 32KB
  int*   eidx   = (int*)(ws + 32832);                            // 64B
  float* egate  = (float*)(ws + 32896);                          // 64B
  unsigned short* xb = (unsigned short*)(ws + 65536);            // 32MB
  unsigned short* wb = (unsigned short*)(ws + 65536 + (size_t)Bb * Ss * Dd * 2);

  hipMemsetAsync(pooled, 0, Bb * Dd * sizeof(float), stream);

  k_prep<<<768, 256, 0, stream>>>(x, xb, expert_w, wb, pooled);
  k_gates<<<1, 256, 0, stream>>>(pooled, gate_w, gate_b, eidx, egate);
  k_moe_gemm<<<(Ss / BM) * (Oo / BN) * Bb, 512, 0, stream>>>(xb, wb, eidx, egate,
                                                             expert_b, out);
}

// Round 12
// 271.704 us; speedup vs baseline: 1.3779x; 1.0152x over previous
//
#include <hip/hip_runtime.h>
#include <stdint.h>

// Problem sizes (fixed by reference)
constexpr int Bb = 8;      // batch
constexpr int Ss = 2048;   // sequence
constexpr int Dd = 1024;   // model dim (K of GEMM)
constexpr int Oo = 1024;   // expert out dim (N of GEMM)
constexpr int Ee = 8;      // experts

typedef __bf16 bf16x8 __attribute__((ext_vector_type(8)));
typedef float  f32x4  __attribute__((ext_vector_type(4)));

__device__ __forceinline__ unsigned short f2bf(float f) {
  // round-to-nearest-even fp32 -> bf16 (inputs are finite)
  unsigned int u = __float_as_uint(f);
  unsigned int r = (u + 0x7fffu + ((u >> 16) & 1u)) >> 16;
  return (unsigned short)r;
}

__device__ __forceinline__ void gl_lds16(const void* g, void* l) {
  // async 16B global -> LDS; LDS dest is wave-uniform base + lane*16
  __builtin_amdgcn_global_load_lds((const __attribute__((address_space(1))) void*)g,
                                   (__attribute__((address_space(3))) void*)l,
                                   16, 0, 0);
}

// ---------------------------------------------------------------------------
// Kernel P: fence-free balanced prep (verbatim from R8/R9). 768 blocks of 256.
// ---------------------------------------------------------------------------
__global__ __launch_bounds__(256) void k_prep(
    const float* __restrict__ x, unsigned short* __restrict__ xb,
    const float* __restrict__ w, unsigned short* __restrict__ wb,
    float* __restrict__ pooled) {
  const int bid = blockIdx.x;
  const int t = threadIdx.x;

  if (bid >= 512) {
    const size_t base = (size_t)(bid - 512) * 32768 + t * 4;
    const float4* wp = (const float4*)(w + base);
    ushort4* wo = (ushort4*)(wb + base);
#pragma unroll 8
    for (int it = 0; it < 32; ++it) {
      float4 v = wp[(size_t)it * 256];
      ushort4 o;
      o.x = f2bf(v.x); o.y = f2bf(v.y); o.z = f2bf(v.z); o.w = f2bf(v.w);
      wo[(size_t)it * 256] = o;
    }
    return;
  }

  const int b  = bid >> 6;
  const int sc = bid & 63;
  const size_t base = (size_t)b * Ss * Dd + (size_t)sc * 32 * Dd + t * 4;
  const float4* xp = (const float4*)(x + base);
  ushort4* xo = (ushort4*)(xb + base);
  float4 acc = make_float4(0.f, 0.f, 0.f, 0.f);
#pragma unroll 8
  for (int s = 0; s < 32; ++s) {
    float4 v = xp[(size_t)s * (Dd / 4)];
    acc.x += v.x; acc.y += v.y; acc.z += v.z; acc.w += v.w;
    ushort4 o;
    o.x = f2bf(v.x); o.y = f2bf(v.y); o.z = f2bf(v.z); o.w = f2bf(v.w);
    xo[(size_t)s * (Dd / 4)] = o;
  }
  float* pd = pooled + b * Dd + t * 4;
  atomicAdd(pd + 0, acc.x);
  atomicAdd(pd + 1, acc.y);
  atomicAdd(pd + 2, acc.z);
  atomicAdd(pd + 3, acc.w);
}

// ---------------------------------------------------------------------------
// Kernel B: gates (verbatim from R8/R9). One block.
// ---------------------------------------------------------------------------
__global__ __launch_bounds__(256) void k_gates(
    const float* __restrict__ pooled, const float* __restrict__ gw,
    const float* __restrict__ gb, int* __restrict__ eidx,
    float* __restrict__ egate) {
  __shared__ float slog[Bb * Ee];
  const int t = threadIdx.x;
  const int p = t >> 2, part = t & 3;
  const int b = p >> 3, e = p & 7;
  const float4* pv = (const float4*)(pooled + b * Dd + part * 256);
  const float4* wv = (const float4*)(gw + e * Dd + part * 256);
  float s = 0.f;
#pragma unroll
  for (int i = 0; i < 64; ++i) {
    float4 a = pv[i], w = wv[i];
    s += a.x * w.x + a.y * w.y + a.z * w.z + a.w * w.w;
  }
  s += __shfl_xor(s, 1);
  s += __shfl_xor(s, 2);
  if (part == 0) slog[p] = s * (1.0f / (float)Ss) + gb[e];
  __syncthreads();
  if (t < Bb) {
    float m1 = -3.4e38f, m2 = -3.4e38f;
    int i1 = 0, i2 = 0;
#pragma unroll
    for (int i = 0; i < Ee; ++i) {
      const float v = slog[t * Ee + i];
      if (v > m1) { m2 = m1; i2 = i1; m1 = v; i1 = i; }
      else if (v > m2) { m2 = v; i2 = i; }
    }
    const float e2 = expf(m2 - m1);
    const float inv = 1.0f / (1.0f + e2);
    eidx[t * 2 + 0] = i1;
    eidx[t * 2 + 1] = i2;
    egate[t * 2 + 0] = inv;
    egate[t * 2 + 1] = e2 * inv;
  }
}

// ---------------------------------------------------------------------------
// Kernel D: dual-expert GEMM, 8-wave, 2-barrier free-slip schedule.
// BM=256 x BN=128, BK=32, 512 threads (2M x 4N waves), dbuf 2x32KB = 64KB.
// Per K-tile: {bar; STAGE(next tile -> other buf); vmcnt(4); bar;
//   12 ds_read + 32 MFMA with NO internal barriers/waits} — compiler emits
// fine-grained lgkmcnt; waves slip inside the region so LDS reads overlap
// MFMA across the 2 waves/SIMD. All ds_read addrs = base reg + imm.
// Swizzle: 16B unit u of row R at physical u^((R>>1)&3) (same as R9).
// Stage layout (32KB): A[256 rows] @0, B_e0[128] @16384, B_e1[128] @24576.
// ---------------------------------------------------------------------------
constexpr int BM = 256, BN = 128, BK = 32;
constexpr int STG = 32768;
constexpr int B0_OFF = 16384, B1_OFF = 24576;

__global__ __launch_bounds__(512, 2) void k_moe_gemm(
    const unsigned short* __restrict__ xb, const unsigned short* __restrict__ wb,
    const int* __restrict__ eidx, const float* __restrict__ egate,
    const float* __restrict__ expert_b, float* __restrict__ out) {
  __shared__ char lds[2 * STG];   // 64 KB static

  // XCD-aware bijective swizzle: 512 blocks, 8 XCDs -> one batch per XCD.
  const int hw = blockIdx.x;
  const int lg_id = ((hw & 7) << 6) | (hw >> 3);
  const int b  = lg_id >> 6;                // batch == XCD
  const int wg = lg_id & 63;
  const int m0 = (wg & 7) * BM;             // s tile (8)
  const int n0 = (wg >> 3) * BN;            // o tile (8)
  const int t  = threadIdx.x;
  const int lane = t & 63;
  const int wid  = t >> 6;                  // 0..7
  const int wr = wid >> 2;                  // 0..1 (M)
  const int wc = wid & 3;                   // 0..3 (N)
  const int lr = lane & 15;
  const int lg = lane >> 4;

  const int e0 = eidx[b * 2 + 0];
  const int e1 = eidx[b * 2 + 1];
  const float g0 = egate[b * 2 + 0];
  const float g1 = egate[b * 2 + 1];

  // ---- staging geometry: thread t -> srow=t>>2 (0..127), phys unit t&3 ----
  const int srow = t >> 2;
  const int scol = ((t & 3) ^ ((srow >> 1) & 3)) * 8;  // inverse-swizzled col
  const int ldsoff = wid * 1024;                       // wave-uniform dest part

  const unsigned short* gA0 = xb + (size_t)b * Ss * Dd + (size_t)(m0 + srow) * Dd + scol;
  const unsigned short* gA1 = gA0 + (size_t)128 * Dd;
  const unsigned short* gB0 = wb + (size_t)e0 * Oo * Dd + (size_t)(n0 + srow) * Dd + scol;
  const unsigned short* gB1 = wb + (size_t)e1 * Oo * Dd + (size_t)(n0 + srow) * Dd + scol;

  // ---- hoisted ds_read base addresses; frag index -> compile-time imm ----
  const int swz = (lg ^ ((lr >> 1) & 3)) * 16;
  const int adsA0 = (wr * 128 + lr) * 64 + swz;           // + m*1024 imm
  const int adsA1 = adsA0 + STG;                          // buf1
  const int adsB0 = B0_OFF + (wc * 32 + lr) * 64 + swz;   // + e*8192 + n*1024 imm
  const int adsB1 = adsB0 + STG;

  f32x4 acc0[8][2] = {};
  f32x4 acc1[8][2] = {};

  auto STAGE = [&](char* base) {
    gl_lds16(gA0, base + ldsoff);              // A rows 0..127
    gl_lds16(gA1, base + 8192 + ldsoff);       // A rows 128..255
    gl_lds16(gB0, base + B0_OFF + ldsoff);     // B expert0
    gl_lds16(gB1, base + B1_OFF + ldsoff);     // B expert1
    gA0 += BK; gA1 += BK; gB0 += BK; gB1 += BK;
  };

  // free-slip compute region: 12 ds_read + 32 MFMA, no internal syncs
#define COMPUTE(ADSA, ADSB)                                                    \
  {                                                                            \
    bf16x8 af[8], bf0[2], bf1[2];                                              \
    _Pragma("unroll")                                                          \
    for (int m = 0; m < 8; ++m)                                                \
      af[m] = *(const bf16x8*)(lds + (ADSA) + m * 1024);                       \
    _Pragma("unroll")                                                          \
    for (int n = 0; n < 2; ++n) {                                              \
      bf0[n] = *(const bf16x8*)(lds + (ADSB) + n * 1024);                      \
      bf1[n] = *(const bf16x8*)(lds + (ADSB) + 8192 + n * 1024);               \
    }                                                                          \
    __builtin_amdgcn_s_setprio(1);                                             \
    _Pragma("unroll")                                                          \
    for (int m = 0; m < 8; ++m)                                                \
      _Pragma("unroll")                                                        \
      for (int n = 0; n < 2; ++n)                                              \
        acc0[m][n] = __builtin_amdgcn_mfma_f32_16x16x32_bf16(                  \
            af[m], bf0[n], acc0[m][n], 0, 0, 0);                               \
    _Pragma("unroll")                                                          \
    for (int m = 0; m < 8; ++m)                                                \
      _Pragma("unroll")                                                        \
      for (int n = 0; n < 2; ++n)                                              \
        acc1[m][n] = __builtin_amdgcn_mfma_f32_16x16x32_bf16(                  \
            af[m], bf1[n], acc1[m][n], 0, 0, 0);                               \
    __builtin_amdgcn_s_setprio(0);                                             \
  }

  // tile boundary: all waves done reading the buf STAGE will overwrite,
  // then wait own tile-i loads (vmcnt counts newest 4 = tile i+1's).
#define BOUNDARY(STAGEBASE)                                                    \
  __builtin_amdgcn_s_barrier();                                                \
  __builtin_amdgcn_sched_barrier(0);                                           \
  STAGE(STAGEBASE);                                                            \
  asm volatile("s_waitcnt vmcnt(4)" ::: "memory");                             \
  __builtin_amdgcn_s_barrier();                                                \
  __builtin_amdgcn_sched_barrier(0);

  // ---- K loop: 32 K-tiles, unrolled x2 so buffer select is compile-time ----
  STAGE(lds);                                  // tile 0 -> buf0
#pragma unroll 1
  for (int i = 0; i < 15; ++i) {
    BOUNDARY(lds + STG);                       // stage tile 2i+1 -> buf1
    COMPUTE(adsA0, adsB0);                     // compute tile 2i   (buf0)
    BOUNDARY(lds);                             // stage tile 2i+2 -> buf0
    COMPUTE(adsA1, adsB1);                     // compute tile 2i+1 (buf1)
  }
  BOUNDARY(lds + STG);                         // stage tile 31 -> buf1
  COMPUTE(adsA0, adsB0);                       // compute tile 30 (buf0)
  __builtin_amdgcn_s_barrier();
  asm volatile("s_waitcnt vmcnt(0)" ::: "memory");
  __builtin_amdgcn_s_barrier();
  __builtin_amdgcn_sched_barrier(0);
  COMPUTE(adsA1, adsB1);                       // compute tile 31 (buf1)

#undef BOUNDARY
#undef COMPUTE

  // ---- epilogue: out = g0*gelu(acc0+bias0) + g1*gelu(acc1+bias1) ----
#pragma unroll
  for (int n = 0; n < 2; ++n) {
    const int col = n0 + wc * 32 + n * 16 + lr;
    const float bias0 = expert_b[e0 * Oo + col];
    const float bias1 = expert_b[e1 * Oo + col];
#pragma unroll
    for (int m = 0; m < 8; ++m)
#pragma unroll
      for (int r = 0; r < 4; ++r) {
        const int row = m0 + wr * 128 + m * 16 + lg * 4 + r;
        const float v0 = acc0[m][n][r] + bias0;
        const float v1 = acc1[m][n][r] + bias1;
        const float ge0 = 0.5f * v0 * (1.0f + erff(v0 * 0.70710678118654752f));
        const float ge1 = 0.5f * v1 * (1.0f + erff(v1 * 0.70710678118654752f));
        out[(size_t)b * Ss * Oo + (size_t)row * Oo + col] = g0 * ge0 + g1 * ge1;
      }
  }
}

// ---------------------------------------------------------------------------
extern "C" void kernel_launch(void* const* d_in, const int* in_sizes, int n_in,
                              void* d_out, int out_size, void* d_ws, size_t ws_size,
                              hipStream_t stream) {
  const float* x        = (const float*)d_in[0];
  const float* gate_w   = (const float*)d_in[1];
  const float* gate_b   = (const float*)d_in[2];
  const float* expert_w = (const float*)d_in[3];
  const float* expert_b = (const float*)d_in[4];
  float* out = (float*)d_out;

  char* ws = (char*)d_ws;
  float* pooled = (float*)ws;                                    // 32KB
  int*   eidx   = (int*)(ws + 32832);                            // 64B
  float* egate  = (float*)(ws + 32896);                          // 64B
  unsigned short* xb = (unsigned short*)(ws + 65536);            // 32MB
  unsigned short* wb = (unsigned short*)(ws + 65536 + (size_t)Bb * Ss * Dd * 2);

  hipMemsetAsync(pooled, 0, Bb * Dd * sizeof(float), stream);

  k_prep<<<768, 256, 0, stream>>>(x, xb, expert_w, wb, pooled);
  k_gates<<<1, 256, 0, stream>>>(pooled, gate_w, gate_b, eidx, egate);
  k_moe_gemm<<<(Ss / BM) * (Oo / BN) * Bb, 512, 0, stream>>>(xb, wb, eidx, egate,
                                                             expert_b, out);
}